// Round 1
// baseline (145.050 us; speedup 1.0000x reference)
//
#include <hip/hip_runtime.h>
#include <hip/hip_bf16.h>

#define NB 4
#define NQ 1024
#define NKS 1024
#define ND 256
#define NH 8
#define NHD 32
#define NOUT 256

typedef __attribute__((ext_vector_type(8))) short v8s;
typedef __attribute__((ext_vector_type(4))) short v4s;
typedef __attribute__((ext_vector_type(4))) float f32x4;

// ---------------- Kernel 1: QKV + gate projections (f32 VALU GEMM) -------------
// y==0: q_data rows -> Qw (bf16, scaled, [b][h][q][hd]), G (f32 gate logits [b][q][256])
// y==1: m_data rows -> Kw (bf16 [b][h][k][hd]), Vt (bf16 transposed [b][h][hd][k])
__global__ __launch_bounds__(256) void proj_kernel(
    const float* __restrict__ qdata, const float* __restrict__ mdata,
    const float* __restrict__ query_w, const float* __restrict__ key_w,
    const float* __restrict__ value_w, const float* __restrict__ gating_w,
    const float* __restrict__ gating_b,
    __hip_bfloat16* __restrict__ Qw, __hip_bfloat16* __restrict__ Kw,
    __hip_bfloat16* __restrict__ Vt, float* __restrict__ G)
{
  __shared__ float rows[16][256];
  const int t = threadIdx.x;
  const int r0 = blockIdx.x * 16;            // flat row base (b*1024 + pos)
  const bool isQ = (blockIdx.y == 0);
  const float* src = isQ ? qdata : mdata;

  // stage 16 input rows (16KB) coalesced
  const float4* sp = (const float4*)(src + (size_t)r0 * ND);
  float4* ld = (float4*)&rows[0][0];
  #pragma unroll
  for (int i = 0; i < 4; ++i) ld[t + i * 256] = sp[t + i * 256];
  __syncthreads();

  const float* wA = isQ ? query_w : key_w;
  const float* wB = isQ ? gating_w : value_w;
  float accA[16], accB[16];
  #pragma unroll
  for (int r = 0; r < 16; ++r) { accA[r] = 0.f; accB[r] = 0.f; }

  for (int d0 = 0; d0 < 256; d0 += 8) {
    float wa[8], wb[8];
    #pragma unroll
    for (int j = 0; j < 8; ++j) {
      wa[j] = wA[(d0 + j) * 256 + t];
      wb[j] = wB[(d0 + j) * 256 + t];
    }
    #pragma unroll
    for (int r = 0; r < 16; ++r) {
      float4 x0 = *(const float4*)&rows[r][d0];
      float4 x1 = *(const float4*)&rows[r][d0 + 4];
      accA[r] += x0.x*wa[0] + x0.y*wa[1] + x0.z*wa[2] + x0.w*wa[3]
               + x1.x*wa[4] + x1.y*wa[5] + x1.z*wa[6] + x1.w*wa[7];
      accB[r] += x0.x*wb[0] + x0.y*wb[1] + x0.z*wb[2] + x0.w*wb[3]
               + x1.x*wb[4] + x1.y*wb[5] + x1.z*wb[6] + x1.w*wb[7];
    }
  }

  const int h = t >> 5, hd = t & 31;
  if (isQ) {
    const float qscale = 0.1767766952966369f;  // 32^-0.5
    const float gb = gating_b[t];
    #pragma unroll
    for (int r = 0; r < 16; ++r) {
      int row = r0 + r;
      int b = row >> 10, pos = row & 1023;
      Qw[((size_t)(b * NH + h) * NQ + pos) * NHD + hd] = __float2bfloat16(accA[r] * qscale);
      G[(size_t)row * 256 + t] = accB[r] + gb;
    }
  } else {
    #pragma unroll
    for (int r = 0; r < 16; ++r) {
      int row = r0 + r;
      int b = row >> 10, pos = row & 1023;
      Kw[((size_t)(b * NH + h) * NKS + pos) * NHD + hd] = __float2bfloat16(accA[r]);
      Vt[((size_t)(b * NH + h) * NHD + hd) * NKS + pos] = __float2bfloat16(accB[r]);
    }
  }
}

// ---------------- Kernel 2: fused flash attention + logits dump ----------------
// grid = B*H*(Q/64) = 512 blocks, 256 threads (4 waves), each wave: 16 q-rows.
__global__ __launch_bounds__(256) void attn_kernel(
    const __hip_bfloat16* __restrict__ Qw, const __hip_bfloat16* __restrict__ Kw,
    const __hip_bfloat16* __restrict__ Vt,
    const float* __restrict__ bias, const float* __restrict__ nbb,
    float* __restrict__ out_logits, float* __restrict__ WA)
{
  __shared__ float s_bias[1024];
  __shared__ __align__(16) __hip_bfloat16 sK[32][40];       // K tile [k][hd], padded
  __shared__ __align__(16) __hip_bfloat16 sV[32][40];       // V^T tile [hd][k], padded
  __shared__ __align__(16) __hip_bfloat16 sP[4][16][40];    // per-wave P tile [q][k]

  const int tid = threadIdx.x;
  const int lane = tid & 63, wv = tid >> 6;
  const int qt = blockIdx.x & 15;
  const int h  = (blockIdx.x >> 4) & 7;
  const int b  = blockIdx.x >> 7;
  const int c  = lane & 15, g = lane >> 4;
  const int q0 = qt * 64 + wv * 16;
  const size_t bh = (size_t)(b * NH + h);

  // stage full bias row for this b (4KB)
  ((float4*)s_bias)[tid] = ((const float4*)(bias + (size_t)b * NKS))[tid];

  // Q A-fragment: lane holds row q0+c, hd = g*8..g*8+7
  v8s qfrag = *(const v8s*)(Qw + (bh * NQ + q0 + c) * NHD + g * 8);

  f32x4 O0 = {0.f, 0.f, 0.f, 0.f}, O1 = {0.f, 0.f, 0.f, 0.f};
  const float NEG_INF = -__builtin_inff();
  float m[4], lsum[4];
  #pragma unroll
  for (int r = 0; r < 4; ++r) { m[r] = NEG_INF; lsum[r] = 0.f; }

  const int sk = tid >> 3;           // staging row 0..31
  const int sc4 = (tid & 7) * 4;     // staging col (elements)

  const f32x4 zacc = {0.f, 0.f, 0.f, 0.f};

  for (int kt = 0; kt < 32; ++kt) {
    const int k0 = kt * 32;
    // cooperative stage: K tile and V^T tile (8B per thread each)
    *(v4s*)&sK[sk][sc4] = *(const v4s*)(Kw + (bh * NKS + k0 + sk) * NHD + sc4);
    *(v4s*)&sV[sk][sc4] = *(const v4s*)(Vt + (bh * NHD + sk) * NKS + k0 + sc4);
    __syncthreads();

    // S = Q @ K^T for k-cols [k0, k0+32)
    v8s bk0 = *(const v8s*)&sK[c][g * 8];
    v8s bk1 = *(const v8s*)&sK[16 + c][g * 8];
    f32x4 S0 = __builtin_amdgcn_mfma_f32_16x16x32_bf16(qfrag, bk0, zacc, 0, 0, 0);
    f32x4 S1 = __builtin_amdgcn_mfma_f32_16x16x32_bf16(qfrag, bk1, zacc, 0, 0, 0);

    const int col0 = k0 + c, col1 = col0 + 16;
    const float bs0 = s_bias[col0], bs1 = s_bias[col1];
    float l0[4], l1[4];
    #pragma unroll
    for (int r = 0; r < 4; ++r) {
      const int qrow = q0 + g * 4 + r;
      const size_t lbase = (bh * NQ + qrow) * (size_t)NKS;
      out_logits[lbase + col0] = S0[r];
      out_logits[lbase + col1] = S1[r];
      const size_t nbase = ((size_t)h * NQ + qrow) * NKS;
      l0[r] = S0[r] + bs0 + nbb[nbase + col0];
      l1[r] = S1[r] + bs1 + nbb[nbase + col1];
    }

    // online softmax (per q-row: reduce across the 16 lanes of the group)
    #pragma unroll
    for (int r = 0; r < 4; ++r) {
      float x = fmaxf(l0[r], l1[r]);
      x = fmaxf(x, __shfl_xor(x, 1));
      x = fmaxf(x, __shfl_xor(x, 2));
      x = fmaxf(x, __shfl_xor(x, 4));
      x = fmaxf(x, __shfl_xor(x, 8));
      const float mn = fmaxf(m[r], x);
      const float sc = __expf(m[r] - mn);     // first iter: exp(-inf)=0
      const float p0 = __expf(l0[r] - mn);
      const float p1 = __expf(l1[r] - mn);
      float rs = p0 + p1;
      rs += __shfl_xor(rs, 1);
      rs += __shfl_xor(rs, 2);
      rs += __shfl_xor(rs, 4);
      rs += __shfl_xor(rs, 8);
      lsum[r] = lsum[r] * sc + rs;
      m[r] = mn;
      O0[r] *= sc; O1[r] *= sc;
      sP[wv][g * 4 + r][c]      = __float2bfloat16(p0);
      sP[wv][g * 4 + r][16 + c] = __float2bfloat16(p1);
    }

    // PV: O += P @ V   (intra-wave LDS write->read; compiler orders via lgkmcnt)
    v8s pa  = *(const v8s*)&sP[wv][c][g * 8];
    v8s bv0 = *(const v8s*)&sV[c][g * 8];
    v8s bv1 = *(const v8s*)&sV[16 + c][g * 8];
    O0 = __builtin_amdgcn_mfma_f32_16x16x32_bf16(pa, bv0, O0, 0, 0, 0);
    O1 = __builtin_amdgcn_mfma_f32_16x16x32_bf16(pa, bv1, O1, 0, 0, 0);
    __syncthreads();
  }

  #pragma unroll
  for (int r = 0; r < 4; ++r) {
    const int qrow = q0 + g * 4 + r;
    const float inv = 1.0f / lsum[r];
    const size_t wb = ((size_t)b * NQ + qrow) * 256 + h * NHD;
    WA[wb + c]      = O0[r] * inv;
    WA[wb + 16 + c] = O1[r] * inv;
  }
}

// ---------------- Kernel 3: sigmoid gate + output projection ----------------
__global__ __launch_bounds__(256) void outproj_kernel(
    const float* __restrict__ WA, const float* __restrict__ G,
    const float* __restrict__ output_w, const float* __restrict__ output_b,
    float* __restrict__ out)
{
  __shared__ float rows[16][256];
  const int t = threadIdx.x;
  const int r0 = blockIdx.x * 16;
  for (int i = t; i < 4096; i += 256) {
    const int r = i >> 8, dcol = i & 255;
    const size_t idx = (size_t)(r0 + r) * 256 + dcol;
    const float gl = G[idx];
    rows[r][dcol] = WA[idx] * (1.f / (1.f + __expf(-gl)));
  }
  __syncthreads();

  float acc[16];
  const float ob = output_b[t];
  #pragma unroll
  for (int r = 0; r < 16; ++r) acc[r] = ob;

  for (int d0 = 0; d0 < 256; d0 += 8) {
    float w[8];
    #pragma unroll
    for (int j = 0; j < 8; ++j) w[j] = output_w[(d0 + j) * 256 + t];
    #pragma unroll
    for (int r = 0; r < 16; ++r) {
      float4 x0 = *(const float4*)&rows[r][d0];
      float4 x1 = *(const float4*)&rows[r][d0 + 4];
      acc[r] += x0.x*w[0] + x0.y*w[1] + x0.z*w[2] + x0.w*w[3]
              + x1.x*w[4] + x1.y*w[5] + x1.z*w[6] + x1.w*w[7];
    }
  }
  #pragma unroll
  for (int r = 0; r < 16; ++r)
    out[(size_t)(r0 + r) * 256 + t] = acc[r];
}

extern "C" void kernel_launch(void* const* d_in, const int* in_sizes, int n_in,
                              void* d_out, int out_size, void* d_ws, size_t ws_size,
                              hipStream_t stream) {
  const float* q_data   = (const float*)d_in[0];
  const float* m_data   = (const float*)d_in[1];
  const float* bias     = (const float*)d_in[2];
  const float* nbb      = (const float*)d_in[3];
  const float* query_w  = (const float*)d_in[4];
  const float* key_w    = (const float*)d_in[5];
  const float* value_w  = (const float*)d_in[6];
  const float* gating_w = (const float*)d_in[7];
  const float* gating_b = (const float*)d_in[8];
  const float* output_w = (const float*)d_in[9];
  const float* output_b = (const float*)d_in[10];

  float* out        = (float*)d_out;
  float* out_logits = out + (size_t)NB * NQ * NOUT;   // 1,048,576 floats in

  char* ws = (char*)d_ws;
  __hip_bfloat16* Qw = (__hip_bfloat16*)(ws);                    // 2MB
  __hip_bfloat16* Kw = (__hip_bfloat16*)(ws + (1u << 21));       // 2MB
  __hip_bfloat16* Vt = (__hip_bfloat16*)(ws + (2u << 21));       // 2MB
  float*          G  = (float*)(ws + (3u << 21));                // 4MB
  float*          WA = (float*)(ws + (5u << 21));                // 4MB

  proj_kernel<<<dim3(256, 2), 256, 0, stream>>>(
      q_data, m_data, query_w, key_w, value_w, gating_w, gating_b,
      Qw, Kw, Vt, G);
  attn_kernel<<<512, 256, 0, stream>>>(
      Qw, Kw, Vt, bias, nbb, out_logits, WA);
  outproj_kernel<<<256, 256, 0, stream>>>(
      WA, G, output_w, output_b, out);
}

// Round 2
// 139.495 us; speedup vs baseline: 1.0398x; 1.0398x over previous
//
#include <hip/hip_runtime.h>
#include <hip/hip_bf16.h>

#define NB 4
#define NQ 1024
#define NKS 1024
#define ND 256
#define NH 8
#define NHD 32
#define NOUT 256

typedef __attribute__((ext_vector_type(8))) short v8s;
typedef __attribute__((ext_vector_type(4))) short v4s;
typedef __attribute__((ext_vector_type(4))) float f32x4;

// ---------------- Kernel 1: QKV + gate projections (f32 VALU GEMM) -------------
// y==0: q_data rows -> Qw (bf16, scaled, [b][h][q][hd]), G (f32 gate logits [b][q][256])
// y==1: m_data rows -> Kw (bf16 [b][h][k][hd]), Vt (bf16 transposed [b][h][hd][k])
__global__ __launch_bounds__(256) void proj_kernel(
    const float* __restrict__ qdata, const float* __restrict__ mdata,
    const float* __restrict__ query_w, const float* __restrict__ key_w,
    const float* __restrict__ value_w, const float* __restrict__ gating_w,
    const float* __restrict__ gating_b,
    __hip_bfloat16* __restrict__ Qw, __hip_bfloat16* __restrict__ Kw,
    __hip_bfloat16* __restrict__ Vt, float* __restrict__ G)
{
  __shared__ float rows[16][256];
  const int t = threadIdx.x;
  const int r0 = blockIdx.x * 16;            // flat row base (b*1024 + pos)
  const bool isQ = (blockIdx.y == 0);
  const float* src = isQ ? qdata : mdata;

  const float4* sp = (const float4*)(src + (size_t)r0 * ND);
  float4* ld = (float4*)&rows[0][0];
  #pragma unroll
  for (int i = 0; i < 4; ++i) ld[t + i * 256] = sp[t + i * 256];
  __syncthreads();

  const float* wA = isQ ? query_w : key_w;
  const float* wB = isQ ? gating_w : value_w;
  float accA[16], accB[16];
  #pragma unroll
  for (int r = 0; r < 16; ++r) { accA[r] = 0.f; accB[r] = 0.f; }

  for (int d0 = 0; d0 < 256; d0 += 8) {
    float wa[8], wb[8];
    #pragma unroll
    for (int j = 0; j < 8; ++j) {
      wa[j] = wA[(d0 + j) * 256 + t];
      wb[j] = wB[(d0 + j) * 256 + t];
    }
    #pragma unroll
    for (int r = 0; r < 16; ++r) {
      float4 x0 = *(const float4*)&rows[r][d0];
      float4 x1 = *(const float4*)&rows[r][d0 + 4];
      accA[r] += x0.x*wa[0] + x0.y*wa[1] + x0.z*wa[2] + x0.w*wa[3]
               + x1.x*wa[4] + x1.y*wa[5] + x1.z*wa[6] + x1.w*wa[7];
      accB[r] += x0.x*wb[0] + x0.y*wb[1] + x0.z*wb[2] + x0.w*wb[3]
               + x1.x*wb[4] + x1.y*wb[5] + x1.z*wb[6] + x1.w*wb[7];
    }
  }

  const int h = t >> 5, hd = t & 31;
  if (isQ) {
    const float qscale = 0.1767766952966369f;  // 32^-0.5
    const float gb = gating_b[t];
    #pragma unroll
    for (int r = 0; r < 16; ++r) {
      int row = r0 + r;
      int b = row >> 10, pos = row & 1023;
      Qw[((size_t)(b * NH + h) * NQ + pos) * NHD + hd] = __float2bfloat16(accA[r] * qscale);
      G[(size_t)row * 256 + t] = accB[r] + gb;
    }
  } else {
    #pragma unroll
    for (int r = 0; r < 16; ++r) {
      int row = r0 + r;
      int b = row >> 10, pos = row & 1023;
      Kw[((size_t)(b * NH + h) * NKS + pos) * NHD + hd] = __float2bfloat16(accA[r]);
      Vt[((size_t)(b * NH + h) * NHD + hd) * NKS + pos] = __float2bfloat16(accB[r]);
    }
  }
}

// ---------------- Kernel 2: barrier-free fused flash attention ----------------
// 1 wave per block, 16 q-rows per wave. grid = B*H*(Q/16) = 2048.
// K/V MFMA B-fragments loaded straight from global (L2/L3-resident),
// register ping-pong double-buffering, KTILE=64, no __syncthreads.
__global__ __launch_bounds__(64) void attn_kernel(
    const __hip_bfloat16* __restrict__ Qw, const __hip_bfloat16* __restrict__ Kw,
    const __hip_bfloat16* __restrict__ Vt,
    const float* __restrict__ bias, const float* __restrict__ nbb,
    float* __restrict__ out_logits, float* __restrict__ WA)
{
  __shared__ __align__(16) __hip_bfloat16 sP[16][72];   // per-wave P transpose bounce

  const int lane = threadIdx.x;
  const int c = lane & 15, g = lane >> 4;
  const int qt = blockIdx.x & 63;
  const int h  = (blockIdx.x >> 6) & 7;
  const int b  = blockIdx.x >> 9;
  const int q0 = qt * 16;
  const size_t bh = (size_t)(b * NH + h);

  const __hip_bfloat16* Kbase = Kw + bh * NKS * NHD;
  const __hip_bfloat16* Vbase = Vt + bh * NHD * NKS;
  const float* biasb = bias + (size_t)b * NKS;
  const float* nbbb  = nbb + ((size_t)h * NQ + q0) * NKS;

  // Q A-fragment: lane holds row q0+c, hd = g*8..g*8+7
  const v8s qfrag = *(const v8s*)(Qw + (bh * NQ + q0 + c) * NHD + g * 8);

  const f32x4 zacc = {0.f, 0.f, 0.f, 0.f};
  f32x4 O0 = zacc, O1 = zacc;
  const float NEG_INF = -__builtin_inff();
  float m[4], lsum[4];
  #pragma unroll
  for (int r = 0; r < 4; ++r) { m[r] = NEG_INF; lsum[r] = 0.f; }

  // ---- load helpers (all fragments: contiguous 16B per lane) ----
  auto loadKV = [&](int k0, v8s* kf, v8s* vf) {
    kf[0] = *(const v8s*)(Kbase + (k0 +      c) * NHD + g * 8);
    kf[1] = *(const v8s*)(Kbase + (k0 + 16 + c) * NHD + g * 8);
    kf[2] = *(const v8s*)(Kbase + (k0 + 32 + c) * NHD + g * 8);
    kf[3] = *(const v8s*)(Kbase + (k0 + 48 + c) * NHD + g * 8);
    vf[0] = *(const v8s*)(Vbase + (     c) * NKS + k0 +      g * 8);  // hd 0..15,  k 0..31
    vf[1] = *(const v8s*)(Vbase + (16 + c) * NKS + k0 +      g * 8);  // hd 16..31, k 0..31
    vf[2] = *(const v8s*)(Vbase + (     c) * NKS + k0 + 32 + g * 8);  // hd 0..15,  k 32..63
    vf[3] = *(const v8s*)(Vbase + (16 + c) * NKS + k0 + 32 + g * 8);  // hd 16..31, k 32..63
  };
  auto loadBias = [&](int k0, float* nb, float* bv) {
    #pragma unroll
    for (int t = 0; t < 4; ++t) {
      bv[t] = biasb[k0 + t * 16 + c];
      #pragma unroll
      for (int r = 0; r < 4; ++r)
        nb[t * 4 + r] = nbbb[(g * 4 + r) * NKS + k0 + t * 16 + c];
    }
  };

  auto compute = [&](int k0, const v8s* kf, const v8s* vf,
                     const float* nb, const float* bv) {
    f32x4 S[4];
    #pragma unroll
    for (int t = 0; t < 4; ++t)
      S[t] = __builtin_amdgcn_mfma_f32_16x16x32_bf16(qfrag, kf[t], zacc, 0, 0, 0);

    float l[4][4];
    #pragma unroll
    for (int r = 0; r < 4; ++r) {
      const int qrow = q0 + g * 4 + r;
      float* lp = out_logits + (bh * NQ + qrow) * (size_t)NKS + k0 + c;
      #pragma unroll
      for (int t = 0; t < 4; ++t) {
        __builtin_nontemporal_store(S[t][r], lp + t * 16);
        l[r][t] = S[t][r] + bv[t] + nb[t * 4 + r];
      }
    }

    #pragma unroll
    for (int r = 0; r < 4; ++r) {
      float x = fmaxf(fmaxf(l[r][0], l[r][1]), fmaxf(l[r][2], l[r][3]));
      x = fmaxf(x, __shfl_xor(x, 1));
      x = fmaxf(x, __shfl_xor(x, 2));
      x = fmaxf(x, __shfl_xor(x, 4));
      x = fmaxf(x, __shfl_xor(x, 8));
      const float mn = fmaxf(m[r], x);
      const float sc = __expf(m[r] - mn);          // first iter: exp(-inf)=0
      float p[4];
      float rs = 0.f;
      #pragma unroll
      for (int t = 0; t < 4; ++t) { p[t] = __expf(l[r][t] - mn); rs += p[t]; }
      rs += __shfl_xor(rs, 1);
      rs += __shfl_xor(rs, 2);
      rs += __shfl_xor(rs, 4);
      rs += __shfl_xor(rs, 8);
      lsum[r] = lsum[r] * sc + rs;
      m[r] = mn;
      O0[r] *= sc; O1[r] *= sc;
      #pragma unroll
      for (int t = 0; t < 4; ++t)
        sP[g * 4 + r][t * 16 + c] = __float2bfloat16(p[t]);
    }

    // PV: O += P @ V (intra-wave LDS transpose bounce; lgkmcnt-ordered)
    const v8s pa0 = *(const v8s*)&sP[c][g * 8];         // k 0..31
    const v8s pa1 = *(const v8s*)&sP[c][32 + g * 8];    // k 32..63
    O0 = __builtin_amdgcn_mfma_f32_16x16x32_bf16(pa0, vf[0], O0, 0, 0, 0);
    O0 = __builtin_amdgcn_mfma_f32_16x16x32_bf16(pa1, vf[2], O0, 0, 0, 0);
    O1 = __builtin_amdgcn_mfma_f32_16x16x32_bf16(pa0, vf[1], O1, 0, 0, 0);
    O1 = __builtin_amdgcn_mfma_f32_16x16x32_bf16(pa1, vf[3], O1, 0, 0, 0);
  };

  // ---- main loop: register ping-pong double buffering, KTILE=64 ----
  v8s kfA[4], vfA[4], kfB[4], vfB[4];
  float nbA[16], bvA[4], nbB[16], bvB[4];

  loadKV(0, kfA, vfA);
  loadBias(0, nbA, bvA);
  #pragma unroll 1
  for (int kt = 0; kt < 16; kt += 2) {
    loadKV((kt + 1) * 64, kfB, vfB);
    loadBias((kt + 1) * 64, nbB, bvB);
    compute(kt * 64, kfA, vfA, nbA, bvA);
    if (kt + 2 < 16) {
      loadKV((kt + 2) * 64, kfA, vfA);
      loadBias((kt + 2) * 64, nbA, bvA);
    }
    compute((kt + 1) * 64, kfB, vfB, nbB, bvB);
  }

  #pragma unroll
  for (int r = 0; r < 4; ++r) {
    const int qrow = q0 + g * 4 + r;
    const float inv = 1.0f / lsum[r];
    float* wp = WA + ((size_t)b * NQ + qrow) * 256 + h * NHD;
    wp[c]      = O0[r] * inv;
    wp[16 + c] = O1[r] * inv;
  }
}

// ---------------- Kernel 3: sigmoid gate + output projection ----------------
__global__ __launch_bounds__(256) void outproj_kernel(
    const float* __restrict__ WA, const float* __restrict__ G,
    const float* __restrict__ output_w, const float* __restrict__ output_b,
    float* __restrict__ out)
{
  __shared__ float rows[16][256];
  const int t = threadIdx.x;
  const int r0 = blockIdx.x * 16;
  for (int i = t; i < 4096; i += 256) {
    const int r = i >> 8, dcol = i & 255;
    const size_t idx = (size_t)(r0 + r) * 256 + dcol;
    const float gl = G[idx];
    rows[r][dcol] = WA[idx] * (1.f / (1.f + __expf(-gl)));
  }
  __syncthreads();

  float acc[16];
  const float ob = output_b[t];
  #pragma unroll
  for (int r = 0; r < 16; ++r) acc[r] = ob;

  for (int d0 = 0; d0 < 256; d0 += 8) {
    float w[8];
    #pragma unroll
    for (int j = 0; j < 8; ++j) w[j] = output_w[(d0 + j) * 256 + t];
    #pragma unroll
    for (int r = 0; r < 16; ++r) {
      float4 x0 = *(const float4*)&rows[r][d0];
      float4 x1 = *(const float4*)&rows[r][d0 + 4];
      acc[r] += x0.x*w[0] + x0.y*w[1] + x0.z*w[2] + x0.w*w[3]
              + x1.x*w[4] + x1.y*w[5] + x1.z*w[6] + x1.w*w[7];
    }
  }
  #pragma unroll
  for (int r = 0; r < 16; ++r)
    out[(size_t)(r0 + r) * 256 + t] = acc[r];
}

extern "C" void kernel_launch(void* const* d_in, const int* in_sizes, int n_in,
                              void* d_out, int out_size, void* d_ws, size_t ws_size,
                              hipStream_t stream) {
  const float* q_data   = (const float*)d_in[0];
  const float* m_data   = (const float*)d_in[1];
  const float* bias     = (const float*)d_in[2];
  const float* nbb      = (const float*)d_in[3];
  const float* query_w  = (const float*)d_in[4];
  const float* key_w    = (const float*)d_in[5];
  const float* value_w  = (const float*)d_in[6];
  const float* gating_w = (const float*)d_in[7];
  const float* gating_b = (const float*)d_in[8];
  const float* output_w = (const float*)d_in[9];
  const float* output_b = (const float*)d_in[10];

  float* out        = (float*)d_out;
  float* out_logits = out + (size_t)NB * NQ * NOUT;   // 1,048,576 floats in

  char* ws = (char*)d_ws;
  __hip_bfloat16* Qw = (__hip_bfloat16*)(ws);                    // 2MB
  __hip_bfloat16* Kw = (__hip_bfloat16*)(ws + (1u << 21));       // 2MB
  __hip_bfloat16* Vt = (__hip_bfloat16*)(ws + (2u << 21));       // 2MB
  float*          G  = (float*)(ws + (3u << 21));                // 4MB
  float*          WA = (float*)(ws + (5u << 21));                // 4MB

  proj_kernel<<<dim3(256, 2), 256, 0, stream>>>(
      q_data, m_data, query_w, key_w, value_w, gating_w, gating_b,
      Qw, Kw, Vt, G);
  attn_kernel<<<2048, 64, 0, stream>>>(
      Qw, Kw, Vt, bias, nbb, out_logits, WA);
  outproj_kernel<<<256, 256, 0, stream>>>(
      WA, G, output_w, output_b, out);
}